// Round 1
// baseline (86.358 us; speedup 1.0000x reference)
//
#include <hip/hip_runtime.h>
#include <math.h>

// SphereInterLoss: brute-force 10-NN (by center distance) per sphere, then
// top_dist = min over NN of (||cn-cm|| - rn - rm); out = mean over batches of
// var(top_dist, ddof=1).
//
// Strategy: branchless top-11 selection with v_med3_u32 on packed keys
// (d2-bits high 20 | index low 12). Self has d2 == exact 0 -> key == n ->
// always sorts first -> dropped after merge. 4 m-segments per query for
// occupancy (512 blocks x 256 thr = 2 blocks/CU, 2 waves/SIMD), wave-uniform
// m loop -> LDS broadcast reads (no bank conflicts).

#define NB 8
#define NN 4096
#define QPB 64          // queries per block (= lanes per wave)
#define SEG 4           // m-range segments (= waves per block)
#define SEGLEN (NN / SEG)

__device__ __forceinline__ unsigned med3u(unsigned a, unsigned b, unsigned c) {
    unsigned d;
    asm("v_med3_u32 %0, %1, %2, %3" : "=v"(d) : "v"(a), "v"(b), "v"(c));
    return d;
}

__device__ __forceinline__ unsigned minu(unsigned a, unsigned b) {
    return a < b ? a : b;
}

// insert u into ascending k[0..10], dropping the max. All indices static
// after unroll -> stays in registers.
__device__ __forceinline__ void insert11(unsigned k[11], unsigned u) {
#pragma unroll
    for (int j = 10; j >= 1; --j) k[j] = med3u(k[j - 1], k[j], u);
    k[0] = minu(k[0], u);
}

__global__ __launch_bounds__(256, 2)
void knn_kernel(const float4* __restrict__ spheres, float* __restrict__ top_dist) {
    __shared__ float4 c4[NN];                 // {x, y, z, |c|^2}  64 KB
    __shared__ unsigned mrg[QPB][SEG][11];    // 11 KB

    const int b      = blockIdx.x >> 6;       // NN/QPB = 64 chunks per batch
    const int qchunk = blockIdx.x & 63;
    const int tid    = threadIdx.x;
    const int lane   = tid & 63;
    const int seg    = tid >> 6;

    const float4* sp = spheres + (size_t)b * NN;

    // stage centers + squared norms into LDS (radius replaced by |c|^2)
    for (int i = tid; i < NN; i += 256) {
        float4 s = sp[i];
        s.w = fmaf(s.x, s.x, fmaf(s.y, s.y, s.z * s.z));
        c4[i] = s;
    }
    __syncthreads();

    const int n = qchunk * QPB + lane;        // this lane's query index
    const float4 q = c4[n];                   // q.w = |c_n|^2

    unsigned k[11];
#pragma unroll
    for (int j = 0; j < 11; ++j) k[j] = 0xFFFFFFFFu;

    const int mbase = seg * SEGLEN;
#pragma unroll 4
    for (int i = 0; i < SEGLEN; ++i) {
        float4 c = c4[mbase + i];             // wave-uniform addr -> broadcast
        float dot = fmaf(q.x, c.x, fmaf(q.y, c.y, q.z * c.z));
        float d2  = fmaf(-2.0f, dot, q.w + c.w);
        d2 = fmaxf(d2, 0.0f);                 // guard rounding-negative d2
        unsigned u = (__float_as_uint(d2) & 0xFFFFF000u) | (unsigned)(mbase + i);
        insert11(k, u);
    }

    // publish per-segment top-11, merge in wave 0
#pragma unroll
    for (int j = 0; j < 11; ++j) mrg[lane][seg][j] = k[j];
    __syncthreads();

    if (seg == 0) {
#pragma unroll
        for (int sg = 1; sg < SEG; ++sg)
#pragma unroll
            for (int j = 0; j < 11; ++j)
                insert11(k, mrg[lane][sg][j]);

        // k[0] is self (key == n, strictly smallest). Evaluate k[1..10].
        const float* spf = (const float*)sp;
        const float rn = spf[4 * n + 3];
        float best = 1e30f;
#pragma unroll
        for (int j = 1; j <= 10; ++j) {
            int m = (int)(k[j] & 0xFFFu);
            float4 c = c4[m];
            float dx = q.x - c.x, dy = q.y - c.y, dz = q.z - c.z;
            float dis = sqrtf(fmaf(dx, dx, fmaf(dy, dy, dz * dz)));
            float rm = spf[4 * m + 3];
            best = fminf(best, dis - (rn + rm));
        }
        top_dist[b * NN + n] = best;
    }
}

// per-batch variance (ddof=1), two-pass for accuracy
__global__ void var_kernel(const float* __restrict__ td, float* __restrict__ vars) {
    __shared__ float red[256];
    const int b = blockIdx.x, t = threadIdx.x;
    const float* x = td + b * NN;

    float s = 0.0f;
    for (int i = t; i < NN; i += 256) s += x[i];
    red[t] = s;
    __syncthreads();
    for (int o = 128; o > 0; o >>= 1) {
        if (t < o) red[t] += red[t + o];
        __syncthreads();
    }
    const float mu = red[0] / (float)NN;
    __syncthreads();

    float ss = 0.0f;
    for (int i = t; i < NN; i += 256) {
        float d = x[i] - mu;
        ss = fmaf(d, d, ss);
    }
    red[t] = ss;
    __syncthreads();
    for (int o = 128; o > 0; o >>= 1) {
        if (t < o) red[t] += red[t + o];
        __syncthreads();
    }
    if (t == 0) vars[b] = red[0] / (float)(NN - 1);
}

__global__ void fin_kernel(const float* __restrict__ vars, float* __restrict__ out) {
    if (threadIdx.x == 0) {
        float s = 0.0f;
        for (int b = 0; b < NB; ++b) s += vars[b];
        out[0] = s / (float)NB;
    }
}

extern "C" void kernel_launch(void* const* d_in, const int* in_sizes, int n_in,
                              void* d_out, int out_size, void* d_ws, size_t ws_size,
                              hipStream_t stream) {
    const float4* spheres = (const float4*)d_in[0];
    float* td   = (float*)d_ws;               // [NB*NN] top_dist
    float* vars = td + NB * NN;               // [NB]
    float* out  = (float*)d_out;

    knn_kernel<<<dim3(NB * (NN / QPB)), dim3(256), 0, stream>>>(spheres, td);
    var_kernel<<<dim3(NB), dim3(256), 0, stream>>>(td, vars);
    fin_kernel<<<dim3(1), dim3(64), 0, stream>>>(vars, out);
}